// Round 10
// baseline (165.397 us; speedup 1.0000x reference)
//
#include <hip/hip_runtime.h>

#define B_   8
#define D_   256
#define HW_  16384
#define NC_  48     // NCLS*K
#define KO_  128    // key channels
#define PT_  32     // pixels per tile
#define SPX_ 832    // padded sel stride (>= 819)

using bf16x8 = __attribute__((ext_vector_type(8))) short;
using f32x4  = __attribute__((ext_vector_type(4))) float;
typedef unsigned long long ull;

__device__ __forceinline__ unsigned short f2bf(float f) {
  unsigned int u = __float_as_uint(f);
  u += 0x7FFFu + ((u >> 16) & 1u);   // RNE
  return (unsigned short)(u >> 16);
}
__device__ __forceinline__ ull pack4bf(float a, float b, float c, float d) {
  return (ull)f2bf(a) | ((ull)f2bf(b) << 16)
       | ((ull)f2bf(c) << 32) | ((ull)f2bf(d) << 48);
}

// ---------------- P1: q = Wq.protos + bq ; M = q.Wk packed ; beta ; map init ; pixlist ----------------
__global__ __launch_bounds__(256) void p1_kernel(
    const float* __restrict__ protos, const float* __restrict__ Wq,
    const float* __restrict__ bq, const float* __restrict__ Wk,
    const float* __restrict__ bk, const int* __restrict__ xc,
    const int* __restrict__ yc,
    unsigned short* __restrict__ m_pk, float* __restrict__ beta,
    float* __restrict__ protos_out, int* __restrict__ map_i,
    int* __restrict__ pixlist, int pcnt) {
  __shared__ float qs[KO_];
  __shared__ float sc2[2][KO_][2];
  const int c = blockIdx.x;   // 0..47
  const int b = blockIdx.y;   // 0..7
  const int t = threadIdx.x;  // 0..255
  const int o = t & 127, h = t >> 7;
  const int i = c >> 3;
  const float* pp = protos + ((size_t)b * NC_ + c) * D_;
  // phase A: q = Wq.proto + bq (K-split over h)
  {
    const float* wq = Wq + ((size_t)i * KO_ + o) * D_ + h * 128;
    const float* ph = pp + h * 128;
    float acc = 0.f;
    for (int d = 0; d < 128; d += 4) {
      float4 wv = *(const float4*)(wq + d);
      float4 pv = *(const float4*)(ph + d);
      acc += wv.x * pv.x + wv.y * pv.y + wv.z * pv.z + wv.w * pv.w;
    }
    sc2[h][o][0] = acc;
  }
  __syncthreads();
  if (h == 0) {
    float q = sc2[0][o][0] + sc2[1][o][0] + bq[i * KO_ + o];
    qs[o] = q;
    protos_out[((size_t)c * B_ + b) * KO_ + o] = q;
  }
  __syncthreads();
  // phase B: M[c][2o..2o+1], K-split over h
  {
    float m0 = 0.f, m1 = 0.f;
    for (int oo = h * 64; oo < h * 64 + 64; ++oo) {
      float2 wv = *(const float2*)(Wk + (size_t)oo * D_ + o * 2);
      float qv = qs[oo];
      m0 += qv * wv.x; m1 += qv * wv.y;
    }
    sc2[h][o][0] = m0; sc2[h][o][1] = m1;
  }
  __syncthreads();
  if (h == 0) {
    float M0 = sc2[0][o][0] + sc2[1][o][0];
    float M1 = sc2[0][o][1] + sc2[1][o][1];
    const int ks = o >> 4, gg = (o >> 2) & 3, ii = (o & 3) * 2;
    const int ct = c >> 4, lrr = c & 15;
    const size_t fidx = ((size_t)(b * 24 + ks * 3 + ct) * 64 + gg * 16 + lrr) * 8 + ii;
    *(unsigned*)(m_pk + fidx) = (unsigned)f2bf(M0) | ((unsigned)f2bf(M1) << 16);
  }
  // phase C: beta = q.bk (wave 0)
  if (t < 64) {
    float p = qs[t] * bk[t] + qs[t + 64] * bk[t + 64];
    for (int off = 32; off; off >>= 1) p += __shfl_down(p, off);
    if (t == 0) beta[b * NC_ + c] = p;
  }
  // phase D: map init (-1 everywhere) ; phase E: pixlist
  const int gid = (b * NC_ + c) * 256 + t;
  if (gid < B_ * HW_ / 4) map_i[gid] = -1;
  if (gid < pcnt) pixlist[gid] = xc[gid] * 128 + yc[gid];
}

// ---------------- PA: coalesced extract of sampled columns ----------------
// Block (d,b): stream row feats[b][d][:] through LDS in 8KB chunks (fully
// coalesced dwordx4), scatter the 819 sampled pixels to sel[b][d][sp].
__global__ __launch_bounds__(256) void pa_kernel(
    const float* __restrict__ feats, const int* __restrict__ pixlist, int pcnt,
    float* __restrict__ sel) {
  __shared__ float row[2048];
  __shared__ int pl[1024];
  const int d = blockIdx.x, b = blockIdx.y, t = threadIdx.x;
  for (int i = t; i < pcnt; i += 256) pl[i] = pixlist[i];
  const float* fr = feats + ((size_t)b * D_ + d) * HW_;
  float* so = sel + ((size_t)b * D_ + d) * SPX_;
  for (int ch = 0; ch < 8; ++ch) {
    const int c0 = ch * 2048;
    __syncthreads();   // pl ready / prev chunk consumed
    #pragma unroll
    for (int i = 0; i < 2; ++i)
      *(float4*)(row + i * 1024 + t * 4) = *(const float4*)(fr + c0 + i * 1024 + t * 4);
    __syncthreads();
    #pragma unroll
    for (int k = 0; k < 4; ++k) {
      const int sp = k * 256 + t;
      if (sp < pcnt) {
        int off = pl[sp] - c0;
        if ((unsigned)off < 2048u) so[sp] = row[off];
      }
    }
  }
}

// ---------------- P2B: argmin per sampled pixel (R9-verbatim arithmetic, sel-sourced) ----------------
__global__ __launch_bounds__(256) void p2b_kernel(
    const float* __restrict__ sel, const float* __restrict__ protos,
    const int* __restrict__ pixlist, signed char* __restrict__ map) {
  __shared__ float selc[B_][D_];     // 8 KB
  __shared__ float d2b[B_][NC_];     // 1.5 KB
  const int sp = blockIdx.x;
  const int t  = threadIdx.x;        // 0..255
  #pragma unroll
  for (int b = 0; b < B_; ++b)
    selc[b][t] = sel[((size_t)b * D_ + t) * SPX_ + sp];
  __syncthreads();
  for (int pair = t; pair < B_ * NC_; pair += 256) {
    const int b = pair / NC_, c = pair % NC_;
    const float* pf = protos + ((size_t)b * NC_ + c) * D_;
    const float* sl = selc[b];
    float nrm = 0.f, dot = 0.f;
    for (int d = 0; d < D_; d += 4) {
      float4 pv = *(const float4*)(pf + d);
      float4 sv = *(const float4*)(sl + d);
      nrm += pv.x * pv.x + pv.y * pv.y + pv.z * pv.z + pv.w * pv.w;
      dot += pv.x * sv.x + pv.y * sv.y + pv.z * sv.z + pv.w * sv.w;
    }
    d2b[b][c] = nrm - 2.f * dot;
  }
  __syncthreads();
  if (t < B_) {
    float best = d2b[t][0]; int bi = 0;
    for (int c = 1; c < NC_; ++c) {
      float v = d2b[t][c];
      if (v < best) { best = v; bi = c; }   // strict '<' keeps first index (np.argmin)
    }
    map[(size_t)t * HW_ + pixlist[sp]] = (signed char)bi;
  }
}

// ---------------- M: fused replace + sim GEMM + softmax + outputs (R9-verified) ----------------
__global__ __launch_bounds__(128, 2) void m_kernel(
    const float* __restrict__ feats, const float* __restrict__ protos,
    const unsigned short* __restrict__ m_pk, const float* __restrict__ beta,
    const signed char* __restrict__ map,
    float* __restrict__ out_assp, float* __restrict__ out_wmax,
    float* __restrict__ out_sim, float* __restrict__ out_wmean) {
  __shared__ __align__(16) unsigned short Fb[PT_ * 256];   // 16 KB
  __shared__ float wm[PT_];
  __shared__ signed char map_s[PT_];

  const int tid  = threadIdx.x;   // 0..127
  const int lane = tid & 63;
  const int wid  = tid >> 6;      // 0..1
  const int g    = lane >> 4;     // 0..3
  const int lr   = lane & 15;
  const int b    = blockIdx.y;
  const int p0   = blockIdx.x * PT_;

  if (tid < PT_) map_s[tid] = map[(size_t)b * HW_ + p0 + tid];
  __syncthreads();

  unsigned char* fbB = (unsigned char*)Fb;
  const int x  = tid & 7;     // pixel quad: pixels x*4..x*4+3
  const int dr = tid >> 3;    // 0..15

  // ---- stage: 16 dwordx4 loads, in-reg substitute+transpose, 16 ds_write_b64 ----
  float V[64];   // V[it*16 + k*4 + j] = F[it*64+dr*4+k][x*4+j]
  {
    const float* fb = feats + (size_t)b * D_ * HW_ + p0 + x * 4;
    const float* prb = protos + (size_t)b * NC_ * D_;
    int cj[4];
    #pragma unroll
    for (int j = 0; j < 4; ++j) cj[j] = map_s[x * 4 + j];
    #pragma unroll
    for (int it = 0; it < 4; ++it) {
      const int d0 = it * 64 + dr * 4;
      #pragma unroll
      for (int k = 0; k < 4; ++k) {
        float4 tv = *(const float4*)(fb + (size_t)(d0 + k) * HW_);
        V[it*16 + k*4 + 0] = tv.x; V[it*16 + k*4 + 1] = tv.y;
        V[it*16 + k*4 + 2] = tv.z; V[it*16 + k*4 + 3] = tv.w;
      }
      #pragma unroll
      for (int j = 0; j < 4; ++j) {
        if (cj[j] >= 0) {
          float4 pv = *(const float4*)(prb + (size_t)cj[j] * D_ + d0);
          V[it*16 + 0*4 + j] = pv.x; V[it*16 + 1*4 + j] = pv.y;
          V[it*16 + 2*4 + j] = pv.z; V[it*16 + 3*4 + j] = pv.w;
        }
      }
      #pragma unroll
      for (int j = 0; j < 4; ++j) {
        const int pw = x * 4 + j;
        const unsigned X = (unsigned)(((pw & 7) << 4) ^ ((pw >> 3) << 3));
        *(ull*)(fbB + pw * 512 + ((unsigned)(d0 * 2) ^ X)) =
            pack4bf(V[it*16 + 0*4 + j], V[it*16 + 1*4 + j],
                    V[it*16 + 2*4 + j], V[it*16 + 3*4 + j]);
      }
    }
  }
  __syncthreads();

  // ---- sim GEMM: sim[c][p] = M(48x256) x F(256x32) + beta ----
  const int p = wid * 16 + lr;
  const unsigned Xp = (unsigned)(((p & 7) << 4) ^ ((p >> 3) << 3));
  f32x4 sacc[3] = {};
  {
    const unsigned short* apk = m_pk + (size_t)b * 24 * 64 * 8 + lane * 8;
    #pragma unroll
    for (int ks = 0; ks < 8; ++ks) {
      const unsigned base = (unsigned)(ks * 64 + g * 16);
      ull lo = *(const ull*)(fbB + p * 512 + (base ^ Xp));
      ull hi = *(const ull*)(fbB + p * 512 + ((base + 8) ^ Xp));
      union { ull u[2]; bf16x8 v8; } bu;
      bu.u[0] = lo; bu.u[1] = hi;
      #pragma unroll
      for (int ct = 0; ct < 3; ++ct) {
        bf16x8 af = *(const bf16x8*)(apk + (size_t)(ks * 3 + ct) * 64 * 8);
        sacc[ct] = __builtin_amdgcn_mfma_f32_16x16x32_bf16(af, bu.v8, sacc[ct], 0, 0, 0);
      }
    }
  }

  // ---- + beta, softmax over c (lanes xor 16/32 share a pixel) ----
  #pragma unroll
  for (int ct = 0; ct < 3; ++ct) {
    float4 bt = *(const float4*)(beta + b * NC_ + ct * 16 + g * 4);
    sacc[ct][0] += bt.x; sacc[ct][1] += bt.y;
    sacc[ct][2] += bt.z; sacc[ct][3] += bt.w;
  }
  float m = -3.4e38f;
  #pragma unroll
  for (int ct = 0; ct < 3; ++ct)
    #pragma unroll
    for (int r = 0; r < 4; ++r) m = fmaxf(m, sacc[ct][r]);
  m = fmaxf(m, __shfl_xor(m, 16));
  m = fmaxf(m, __shfl_xor(m, 32));
  const float sc = 1.0f / 6.0f;   // K/C = 8/48
  float s = 0.f;
  #pragma unroll
  for (int ct = 0; ct < 3; ++ct)
    #pragma unroll
    for (int r = 0; r < 4; ++r) s += __expf((sacc[ct][r] - m) * sc);
  s += __shfl_xor(s, 16);
  s += __shfl_xor(s, 32);
  const float wmax = 1.f / s;

  // ---- sim / wmax / wmean stores ----
  const size_t pixg = (size_t)p0 + p;
  #pragma unroll
  for (int ct = 0; ct < 3; ++ct)
    #pragma unroll
    for (int r = 0; r < 4; ++r)
      out_sim[((size_t)b * NC_ + ct * 16 + g * 4 + r) * HW_ + pixg] = sacc[ct][r];
  if (g == 0) {
    wm[p] = wmax;
    out_wmax[(size_t)b * HW_ + pixg] = wmax;
    out_wmean[(size_t)b * HW_ + pixg] = 1.f / 48.f;
  }
  __syncthreads();

  // ---- weighted output from registers (f32 exact) ----
  {
    float4 w4 = *(const float4*)(wm + x * 4);
    float* oa = out_assp + (size_t)b * D_ * HW_ + p0 + x * 4;
    #pragma unroll
    for (int it = 0; it < 4; ++it) {
      const int d0 = it * 64 + dr * 4;
      #pragma unroll
      for (int k = 0; k < 4; ++k) {
        float4 o;
        o.x = V[it*16 + k*4 + 0] * w4.x;
        o.y = V[it*16 + k*4 + 1] * w4.y;
        o.z = V[it*16 + k*4 + 2] * w4.z;
        o.w = V[it*16 + k*4 + 3] * w4.w;
        *(float4*)(oa + (size_t)(d0 + k) * HW_) = o;
      }
    }
  }
}

extern "C" void kernel_launch(void* const* d_in, const int* in_sizes, int n_in,
                              void* d_out, int out_size, void* d_ws, size_t ws_size,
                              hipStream_t stream) {
  const float* feats  = (const float*)d_in[0];
  const float* protos = (const float*)d_in[1];
  const float* Wk     = (const float*)d_in[2];
  const float* bk     = (const float*)d_in[3];
  const float* Wq     = (const float*)d_in[4];
  const float* bq     = (const float*)d_in[5];
  const int*   xc     = (const int*)d_in[6];
  const int*   yc     = (const int*)d_in[7];
  const int    P      = in_sizes[6];   // 819

  float* out       = (float*)d_out;
  float* out_assp  = out;                                  // B*D*HW
  float* out_po    = out_assp + (size_t)B_ * D_ * HW_;     // 48*B*128
  float* out_wmax  = out_po + (size_t)NC_ * B_ * KO_;      // B*HW
  float* out_sim   = out_wmax + (size_t)B_ * HW_;          // B*48*HW
  float* out_wmean = out_sim + (size_t)B_ * NC_ * HW_;     // B*HW

  unsigned char* ws = (unsigned char*)d_ws;
  unsigned short* m_pk = (unsigned short*)ws;                    // 196608 B
  float* beta          = (float*)(ws + 196608);                  // 1536 B
  signed char* map     = (signed char*)(ws + 198144);            // 131072 B
  int* pixlist         = (int*)(ws + 329216);                    // 3584 B
  const size_t sel_off = 332800;
  const size_t sel_bytes = (size_t)B_ * D_ * SPX_ * 4;           // 6815744 B
  // sel: in ws if it fits, else borrow out_assp (fully overwritten by m afterwards)
  float* sel = (ws_size >= sel_off + sel_bytes) ? (float*)(ws + sel_off) : out_assp;

  p1_kernel<<<dim3(NC_, B_), 256, 0, stream>>>(protos, Wq, bq, Wk, bk, xc, yc,
                                               m_pk, beta, out_po, (int*)map, pixlist, P);
  pa_kernel<<<dim3(D_, B_), 256, 0, stream>>>(feats, pixlist, P, sel);
  p2b_kernel<<<dim3(P), 256, 0, stream>>>(sel, protos, pixlist, map);
  m_kernel<<<dim3(HW_ / PT_, B_), 128, 0, stream>>>(feats, protos, m_pk, beta, map,
                                                    out_assp, out_wmax, out_sim, out_wmean);
}

// Round 11
// 147.982 us; speedup vs baseline: 1.1177x; 1.1177x over previous
//
#include <hip/hip_runtime.h>

#define B_   8
#define D_   256
#define HW_  16384
#define NC_  48     // NCLS*K
#define KO_  128    // key channels
#define PT_  32     // pixels per tile
#define WIN_ 512    // pixels per argmin window
#define NW_  32     // HW_/WIN_
#define MAXS_ 96    // max sampled pixels per window (expect ~26 avg, ~45 max)

using bf16x8 = __attribute__((ext_vector_type(8))) short;
using f32x4  = __attribute__((ext_vector_type(4))) float;
typedef unsigned long long ull;

__device__ __forceinline__ unsigned short f2bf(float f) {
  unsigned int u = __float_as_uint(f);
  u += 0x7FFFu + ((u >> 16) & 1u);   // RNE
  return (unsigned short)(u >> 16);
}
__device__ __forceinline__ ull pack4bf(float a, float b, float c, float d) {
  return (ull)f2bf(a) | ((ull)f2bf(b) << 16)
       | ((ull)f2bf(c) << 32) | ((ull)f2bf(d) << 48);
}

// ---------------- P1: q = Wq.protos + bq ; M = q.Wk packed ; beta ; nrm ; map init ; pixlist ----------------
__global__ __launch_bounds__(256) void p1_kernel(
    const float* __restrict__ protos, const float* __restrict__ Wq,
    const float* __restrict__ bq, const float* __restrict__ Wk,
    const float* __restrict__ bk, const int* __restrict__ xc,
    const int* __restrict__ yc,
    unsigned short* __restrict__ m_pk, float* __restrict__ beta,
    float* __restrict__ nrmb, float* __restrict__ protos_out,
    int* __restrict__ map_i, int* __restrict__ pixlist, int pcnt) {
  __shared__ float qs[KO_];
  __shared__ float sc2[2][KO_][2];
  const int c = blockIdx.x;   // 0..47
  const int b = blockIdx.y;   // 0..7
  const int t = threadIdx.x;  // 0..255
  const int o = t & 127, h = t >> 7;
  const int i = c >> 3;
  const float* pp = protos + ((size_t)b * NC_ + c) * D_;
  // phase A: q = Wq.proto + bq (K-split over h)
  {
    const float* wq = Wq + ((size_t)i * KO_ + o) * D_ + h * 128;
    const float* ph = pp + h * 128;
    float acc = 0.f;
    for (int d = 0; d < 128; d += 4) {
      float4 wv = *(const float4*)(wq + d);
      float4 pv = *(const float4*)(ph + d);
      acc += wv.x * pv.x + wv.y * pv.y + wv.z * pv.z + wv.w * pv.w;
    }
    sc2[h][o][0] = acc;
  }
  __syncthreads();
  if (h == 0) {
    float q = sc2[0][o][0] + sc2[1][o][0] + bq[i * KO_ + o];
    qs[o] = q;
    protos_out[((size_t)c * B_ + b) * KO_ + o] = q;
  }
  __syncthreads();
  // phase B: M[c][2o..2o+1], K-split over h
  {
    float m0 = 0.f, m1 = 0.f;
    for (int oo = h * 64; oo < h * 64 + 64; ++oo) {
      float2 wv = *(const float2*)(Wk + (size_t)oo * D_ + o * 2);
      float qv = qs[oo];
      m0 += qv * wv.x; m1 += qv * wv.y;
    }
    sc2[h][o][0] = m0; sc2[h][o][1] = m1;
  }
  __syncthreads();
  if (h == 0) {
    float M0 = sc2[0][o][0] + sc2[1][o][0];
    float M1 = sc2[0][o][1] + sc2[1][o][1];
    const int ks = o >> 4, gg = (o >> 2) & 3, ii = (o & 3) * 2;
    const int ct = c >> 4, lrr = c & 15;
    const size_t fidx = ((size_t)(b * 24 + ks * 3 + ct) * 64 + gg * 16 + lrr) * 8 + ii;
    *(unsigned*)(m_pk + fidx) = (unsigned)f2bf(M0) | ((unsigned)f2bf(M1) << 16);
  }
  // phase C: beta = q.bk (wave 0)
  if (t < 64) {
    float p = qs[t] * bk[t] + qs[t + 64] * bk[t + 64];
    for (int off = 32; off; off >>= 1) p += __shfl_down(p, off);
    if (t == 0) beta[b * NC_ + c] = p;
  }
  // phase C2: nrm = ||proto||^2, EXACT expression tree of the verified p2
  // (serial d += 4, 4-term left-assoc group)
  if (t == 1 || t == 0) {
    if (t == 1) {
      float nn = 0.f;
      for (int d = 0; d < D_; d += 4) {
        float4 pv = *(const float4*)(pp + d);
        nn += pv.x * pv.x + pv.y * pv.y + pv.z * pv.z + pv.w * pv.w;
      }
      nrmb[b * NC_ + c] = nn;
    }
  }
  // phase D: map init (-1 everywhere) ; phase E: pixlist
  const int gid = (b * NC_ + c) * 256 + t;
  if (gid < B_ * HW_ / 4) map_i[gid] = -1;
  if (gid < pcnt) pixlist[gid] = xc[gid] * 128 + yc[gid];
}

// ---------------- P2C: argmin via coalesced feats scan (no sel buffer) ----------------
// Block (w,b): stream feats[b][:, w*512..+512) coalesced, accumulate
// dot[lp][c] for the window's sampled pixels in LDS. d2 expression tree is
// bit-identical to the verified R9 p2 (serial d+=4 groups, nrm - 2*dot).
__global__ __launch_bounds__(256) void p2c_kernel(
    const float* __restrict__ feats, const float* __restrict__ protos,
    const float* __restrict__ nrmb, const int* __restrict__ pixlist, int pcnt,
    signed char* __restrict__ map) {
  __shared__ float protT[D_][52];      // 53 KB, padded stride (bank-safe)
  __shared__ float rowb[8][WIN_];      // 16 KB
  __shared__ float acc[MAXS_][NC_];    // 18 KB
  __shared__ int   lpix[MAXS_];
  __shared__ int   gpix[MAXS_];
  __shared__ int   cnt_s;
  const int w = blockIdx.x;    // 0..31
  const int b = blockIdx.y;    // 0..7
  const int t = threadIdx.x;   // 0..255
  const int w0 = w * WIN_;
  if (t == 0) cnt_s = 0;
  __syncthreads();
  // collect sampled pixels in this window (slot order nondeterministic; output isn't)
  for (int i = t; i < pcnt; i += 256) {
    int px = pixlist[i];
    int off = px - w0;
    if ((unsigned)off < (unsigned)WIN_) {
      int s = atomicAdd(&cnt_s, 1);
      if (s < MAXS_) { lpix[s] = off; gpix[s] = px; }
    }
  }
  // stage protos transposed: protT[d][c]
  const float* prb = protos + (size_t)b * NC_ * D_;
  for (int i = t; i < NC_ * D_ / 4; i += 256) {   // 3072/256 = 12 iters
    int c = i >> 6, d4 = (i & 63) * 4;
    float4 pv = *(const float4*)(prb + c * D_ + d4);
    protT[d4 + 0][c] = pv.x; protT[d4 + 1][c] = pv.y;
    protT[d4 + 2][c] = pv.z; protT[d4 + 3][c] = pv.w;
  }
  for (int i = t; i < MAXS_ * NC_; i += 256) ((float*)acc)[i] = 0.f;
  __syncthreads();
  const int cnt = min(cnt_s, MAXS_);
  const int npair = cnt * NC_;
  const float* fw = feats + (size_t)b * D_ * HW_ + w0;
  for (int dg2 = 0; dg2 < 32; ++dg2) {           // 8 d-rows per iteration
    #pragma unroll
    for (int k = 0; k < 8; ++k) {
      float2 v = *(const float2*)(fw + (size_t)(dg2 * 8 + k) * HW_ + t * 2);
      *(float2*)(&rowb[k][t * 2]) = v;
    }
    __syncthreads();
    for (int pr = t; pr < npair; pr += 256) {
      const int lp = pr / NC_, c = pr % NC_;
      const int px = lpix[lp];
      const int d = dg2 * 8;
      // two sequential 4-term groups: same accumulation order as d+=4 loop
      float t0 = protT[d + 0][c] * rowb[0][px] + protT[d + 1][c] * rowb[1][px]
               + protT[d + 2][c] * rowb[2][px] + protT[d + 3][c] * rowb[3][px];
      float t1 = protT[d + 4][c] * rowb[4][px] + protT[d + 5][c] * rowb[5][px]
               + protT[d + 6][c] * rowb[6][px] + protT[d + 7][c] * rowb[7][px];
      float a = acc[lp][c];
      a += t0;
      a += t1;
      acc[lp][c] = a;
    }
    __syncthreads();
  }
  // per-pixel argmin (strict '<' keeps first index = np.argmin)
  const float* nr = nrmb + b * NC_;
  for (int lp = t; lp < cnt; lp += 256) {
    float best = 3.4e38f; int bi = 0;
    for (int c = 0; c < NC_; ++c) {
      float d2 = nr[c] - 2.f * acc[lp][c];
      if (d2 < best) { best = d2; bi = c; }
    }
    map[(size_t)b * HW_ + gpix[lp]] = (signed char)bi;
  }
}

// ---------------- M: fused replace + sim GEMM + softmax + outputs (R9-verified, unchanged) ----------------
__global__ __launch_bounds__(128, 2) void m_kernel(
    const float* __restrict__ feats, const float* __restrict__ protos,
    const unsigned short* __restrict__ m_pk, const float* __restrict__ beta,
    const signed char* __restrict__ map,
    float* __restrict__ out_assp, float* __restrict__ out_wmax,
    float* __restrict__ out_sim, float* __restrict__ out_wmean) {
  __shared__ __align__(16) unsigned short Fb[PT_ * 256];   // 16 KB
  __shared__ float wm[PT_];
  __shared__ signed char map_s[PT_];

  const int tid  = threadIdx.x;   // 0..127
  const int lane = tid & 63;
  const int wid  = tid >> 6;      // 0..1
  const int g    = lane >> 4;     // 0..3
  const int lr   = lane & 15;
  const int b    = blockIdx.y;
  const int p0   = blockIdx.x * PT_;

  if (tid < PT_) map_s[tid] = map[(size_t)b * HW_ + p0 + tid];
  __syncthreads();

  unsigned char* fbB = (unsigned char*)Fb;
  const int x  = tid & 7;     // pixel quad: pixels x*4..x*4+3
  const int dr = tid >> 3;    // 0..15

  float V[64];   // V[it*16 + k*4 + j] = F[it*64+dr*4+k][x*4+j]
  {
    const float* fb = feats + (size_t)b * D_ * HW_ + p0 + x * 4;
    const float* prb = protos + (size_t)b * NC_ * D_;
    int cj[4];
    #pragma unroll
    for (int j = 0; j < 4; ++j) cj[j] = map_s[x * 4 + j];
    #pragma unroll
    for (int it = 0; it < 4; ++it) {
      const int d0 = it * 64 + dr * 4;
      #pragma unroll
      for (int k = 0; k < 4; ++k) {
        float4 tv = *(const float4*)(fb + (size_t)(d0 + k) * HW_);
        V[it*16 + k*4 + 0] = tv.x; V[it*16 + k*4 + 1] = tv.y;
        V[it*16 + k*4 + 2] = tv.z; V[it*16 + k*4 + 3] = tv.w;
      }
      #pragma unroll
      for (int j = 0; j < 4; ++j) {
        if (cj[j] >= 0) {
          float4 pv = *(const float4*)(prb + (size_t)cj[j] * D_ + d0);
          V[it*16 + 0*4 + j] = pv.x; V[it*16 + 1*4 + j] = pv.y;
          V[it*16 + 2*4 + j] = pv.z; V[it*16 + 3*4 + j] = pv.w;
        }
      }
      #pragma unroll
      for (int j = 0; j < 4; ++j) {
        const int pw = x * 4 + j;
        const unsigned X = (unsigned)(((pw & 7) << 4) ^ ((pw >> 3) << 3));
        *(ull*)(fbB + pw * 512 + ((unsigned)(d0 * 2) ^ X)) =
            pack4bf(V[it*16 + 0*4 + j], V[it*16 + 1*4 + j],
                    V[it*16 + 2*4 + j], V[it*16 + 3*4 + j]);
      }
    }
  }
  __syncthreads();

  const int p = wid * 16 + lr;
  const unsigned Xp = (unsigned)(((p & 7) << 4) ^ ((p >> 3) << 3));
  f32x4 sacc[3] = {};
  {
    const unsigned short* apk = m_pk + (size_t)b * 24 * 64 * 8 + lane * 8;
    #pragma unroll
    for (int ks = 0; ks < 8; ++ks) {
      const unsigned base = (unsigned)(ks * 64 + g * 16);
      ull lo = *(const ull*)(fbB + p * 512 + (base ^ Xp));
      ull hi = *(const ull*)(fbB + p * 512 + ((base + 8) ^ Xp));
      union { ull u[2]; bf16x8 v8; } bu;
      bu.u[0] = lo; bu.u[1] = hi;
      #pragma unroll
      for (int ct = 0; ct < 3; ++ct) {
        bf16x8 af = *(const bf16x8*)(apk + (size_t)(ks * 3 + ct) * 64 * 8);
        sacc[ct] = __builtin_amdgcn_mfma_f32_16x16x32_bf16(af, bu.v8, sacc[ct], 0, 0, 0);
      }
    }
  }

  #pragma unroll
  for (int ct = 0; ct < 3; ++ct) {
    float4 bt = *(const float4*)(beta + b * NC_ + ct * 16 + g * 4);
    sacc[ct][0] += bt.x; sacc[ct][1] += bt.y;
    sacc[ct][2] += bt.z; sacc[ct][3] += bt.w;
  }
  float m = -3.4e38f;
  #pragma unroll
  for (int ct = 0; ct < 3; ++ct)
    #pragma unroll
    for (int r = 0; r < 4; ++r) m = fmaxf(m, sacc[ct][r]);
  m = fmaxf(m, __shfl_xor(m, 16));
  m = fmaxf(m, __shfl_xor(m, 32));
  const float sc = 1.0f / 6.0f;   // K/C = 8/48
  float s = 0.f;
  #pragma unroll
  for (int ct = 0; ct < 3; ++ct)
    #pragma unroll
    for (int r = 0; r < 4; ++r) s += __expf((sacc[ct][r] - m) * sc);
  s += __shfl_xor(s, 16);
  s += __shfl_xor(s, 32);
  const float wmax = 1.f / s;

  const size_t pixg = (size_t)p0 + p;
  #pragma unroll
  for (int ct = 0; ct < 3; ++ct)
    #pragma unroll
    for (int r = 0; r < 4; ++r)
      out_sim[((size_t)b * NC_ + ct * 16 + g * 4 + r) * HW_ + pixg] = sacc[ct][r];
  if (g == 0) {
    wm[p] = wmax;
    out_wmax[(size_t)b * HW_ + pixg] = wmax;
    out_wmean[(size_t)b * HW_ + pixg] = 1.f / 48.f;
  }
  __syncthreads();

  {
    float4 w4 = *(const float4*)(wm + x * 4);
    float* oa = out_assp + (size_t)b * D_ * HW_ + p0 + x * 4;
    #pragma unroll
    for (int it = 0; it < 4; ++it) {
      const int d0 = it * 64 + dr * 4;
      #pragma unroll
      for (int k = 0; k < 4; ++k) {
        float4 o;
        o.x = V[it*16 + k*4 + 0] * w4.x;
        o.y = V[it*16 + k*4 + 1] * w4.y;
        o.z = V[it*16 + k*4 + 2] * w4.z;
        o.w = V[it*16 + k*4 + 3] * w4.w;
        *(float4*)(oa + (size_t)(d0 + k) * HW_) = o;
      }
    }
  }
}

extern "C" void kernel_launch(void* const* d_in, const int* in_sizes, int n_in,
                              void* d_out, int out_size, void* d_ws, size_t ws_size,
                              hipStream_t stream) {
  const float* feats  = (const float*)d_in[0];
  const float* protos = (const float*)d_in[1];
  const float* Wk     = (const float*)d_in[2];
  const float* bk     = (const float*)d_in[3];
  const float* Wq     = (const float*)d_in[4];
  const float* bq     = (const float*)d_in[5];
  const int*   xc     = (const int*)d_in[6];
  const int*   yc     = (const int*)d_in[7];
  const int    P      = in_sizes[6];   // 819

  float* out       = (float*)d_out;
  float* out_assp  = out;                                  // B*D*HW
  float* out_po    = out_assp + (size_t)B_ * D_ * HW_;     // 48*B*128
  float* out_wmax  = out_po + (size_t)NC_ * B_ * KO_;      // B*HW
  float* out_sim   = out_wmax + (size_t)B_ * HW_;          // B*48*HW
  float* out_wmean = out_sim + (size_t)B_ * NC_ * HW_;     // B*HW

  unsigned char* ws = (unsigned char*)d_ws;
  unsigned short* m_pk = (unsigned short*)ws;                    // 196608 B
  float* beta          = (float*)(ws + 196608);                  // 1536 B
  float* nrmb          = (float*)(ws + 198144);                  // 1536 B
  int* pixlist         = (int*)(ws + 199680);                    // 3584 B
  signed char* map     = (signed char*)(ws + 203264);            // 131072 B

  p1_kernel<<<dim3(NC_, B_), 256, 0, stream>>>(protos, Wq, bq, Wk, bk, xc, yc,
                                               m_pk, beta, nrmb, out_po,
                                               (int*)map, pixlist, P);
  p2c_kernel<<<dim3(NW_, B_), 256, 0, stream>>>(feats, protos, nrmb, pixlist, P, map);
  m_kernel<<<dim3(HW_ / PT_, B_), 128, 0, stream>>>(feats, protos, m_pk, beta, map,
                                                    out_assp, out_wmax, out_sim, out_wmean);
}

// Round 12
// 113.527 us; speedup vs baseline: 1.4569x; 1.3035x over previous
//
#include <hip/hip_runtime.h>

#define B_   8
#define D_   256
#define HW_  16384
#define NC_  48     // NCLS*K
#define KO_  128    // key channels
#define PT_  32     // pixels per tile
#define WIN_ 512    // pixels per argmin window
#define NW_  32     // HW_/WIN_
#define NDC_ 4      // d-chunks
#define MAXS_ 64    // max sampled pixels per window (expect ~26, P(>64) ~ 1e-14)

using bf16x8 = __attribute__((ext_vector_type(8))) short;
using f32x4  = __attribute__((ext_vector_type(4))) float;
typedef unsigned long long ull;

__device__ __forceinline__ unsigned short f2bf(float f) {
  unsigned int u = __float_as_uint(f);
  u += 0x7FFFu + ((u >> 16) & 1u);   // RNE
  return (unsigned short)(u >> 16);
}
__device__ __forceinline__ ull pack4bf(float a, float b, float c, float d) {
  return (ull)f2bf(a) | ((ull)f2bf(b) << 16)
       | ((ull)f2bf(c) << 32) | ((ull)f2bf(d) << 48);
}

// ---------------- P1: q = Wq.protos + bq ; M = q.Wk packed ; beta ; nrm ; map init ; pixlist ----------------
__global__ __launch_bounds__(256) void p1_kernel(
    const float* __restrict__ protos, const float* __restrict__ Wq,
    const float* __restrict__ bq, const float* __restrict__ Wk,
    const float* __restrict__ bk, const int* __restrict__ xc,
    const int* __restrict__ yc,
    unsigned short* __restrict__ m_pk, float* __restrict__ beta,
    float* __restrict__ nrmb, float* __restrict__ protos_out,
    int* __restrict__ map_i, int* __restrict__ pixlist, int pcnt) {
  __shared__ float qs[KO_];
  __shared__ float sc2[2][KO_][2];
  const int c = blockIdx.x;   // 0..47
  const int b = blockIdx.y;   // 0..7
  const int t = threadIdx.x;  // 0..255
  const int o = t & 127, h = t >> 7;
  const int i = c >> 3;
  const float* pp = protos + ((size_t)b * NC_ + c) * D_;
  // phase A: q = Wq.proto + bq (K-split over h)
  {
    const float* wq = Wq + ((size_t)i * KO_ + o) * D_ + h * 128;
    const float* ph = pp + h * 128;
    float acc = 0.f;
    for (int d = 0; d < 128; d += 4) {
      float4 wv = *(const float4*)(wq + d);
      float4 pv = *(const float4*)(ph + d);
      acc += wv.x * pv.x + wv.y * pv.y + wv.z * pv.z + wv.w * pv.w;
    }
    sc2[h][o][0] = acc;
  }
  __syncthreads();
  if (h == 0) {
    float q = sc2[0][o][0] + sc2[1][o][0] + bq[i * KO_ + o];
    qs[o] = q;
    protos_out[((size_t)c * B_ + b) * KO_ + o] = q;
  }
  __syncthreads();
  // phase B: M[c][2o..2o+1], K-split over h
  {
    float m0 = 0.f, m1 = 0.f;
    for (int oo = h * 64; oo < h * 64 + 64; ++oo) {
      float2 wv = *(const float2*)(Wk + (size_t)oo * D_ + o * 2);
      float qv = qs[oo];
      m0 += qv * wv.x; m1 += qv * wv.y;
    }
    sc2[h][o][0] = m0; sc2[h][o][1] = m1;
  }
  __syncthreads();
  if (h == 0) {
    float M0 = sc2[0][o][0] + sc2[1][o][0];
    float M1 = sc2[0][o][1] + sc2[1][o][1];
    const int ks = o >> 4, gg = (o >> 2) & 3, ii = (o & 3) * 2;
    const int ct = c >> 4, lrr = c & 15;
    const size_t fidx = ((size_t)(b * 24 + ks * 3 + ct) * 64 + gg * 16 + lrr) * 8 + ii;
    *(unsigned*)(m_pk + fidx) = (unsigned)f2bf(M0) | ((unsigned)f2bf(M1) << 16);
  }
  // phase C: beta = q.bk (wave 0)
  if (t < 64) {
    float p = qs[t] * bk[t] + qs[t + 64] * bk[t + 64];
    for (int off = 32; off; off >>= 1) p += __shfl_down(p, off);
    if (t == 0) beta[b * NC_ + c] = p;
  }
  // phase C2: nrm = ||proto||^2 (same 4-term serial grouping as verified p2)
  if (t == 1) {
    float nn = 0.f;
    for (int d = 0; d < D_; d += 4) {
      float4 pv = *(const float4*)(pp + d);
      nn += pv.x * pv.x + pv.y * pv.y + pv.z * pv.z + pv.w * pv.w;
    }
    nrmb[b * NC_ + c] = nn;
  }
  // phase D: map init (-1 everywhere) ; phase E: pixlist
  const int gid = (b * NC_ + c) * 256 + t;
  if (gid < B_ * HW_ / 4) map_i[gid] = -1;
  if (gid < pcnt) pixlist[gid] = xc[gid] * 128 + yc[gid];
}

// ---------------- PD: partial dots over a 64-d chunk, coalesced feats streaming ----------------
// Block (w*4+dc, b): stream feats[b][dc*64..+64)[w*512..+512), accumulate
// dot partials for the window's sampled pixels in REGISTERS (fixed pair/thread).
__global__ __launch_bounds__(256) void pd_kernel(
    const float* __restrict__ feats, const float* __restrict__ protos,
    const int* __restrict__ pixlist, int pcnt,
    float* __restrict__ pdot, int* __restrict__ cntg, int* __restrict__ gpixg) {
  __shared__ float protT[64][52];    // 13.3 KB (padded stride, bank-safe)
  __shared__ float rowb[8][WIN_];    // 16 KB
  __shared__ int lpix[MAXS_];
  __shared__ int wbase[4];
  __shared__ int cnt_s;
  const int w  = blockIdx.x >> 2;
  const int dc = blockIdx.x & 3;
  const int b  = blockIdx.y;
  const int t  = threadIdx.x;
  const int lane = t & 63, wv = t >> 6;
  const int w0 = w * WIN_;
  if (t == 0) cnt_s = 0;
  __syncthreads();
  // deterministic slot assignment: slot = rank in pixlist order (ballot prefix scan)
  for (int base = 0; base < 1024; base += 256) {
    const int i = base + t;
    bool hit = false; int off = 0;
    if (i < pcnt) { off = pixlist[i] - w0; hit = ((unsigned)off < (unsigned)WIN_); }
    ull bm = __ballot(hit);
    int lpre = __popcll(bm & ((1ull << lane) - 1ull));
    if (lane == 0) wbase[wv] = __popcll(bm);
    __syncthreads();
    int ex = cnt_s;
    #pragma unroll
    for (int W = 0; W < 4; ++W) if (W < wv) ex += wbase[W];
    if (hit) {
      int s = ex + lpre;
      if (s < MAXS_) {
        lpix[s] = off;
        if (dc == 0 && b == 0) gpixg[w * MAXS_ + s] = w0 + off;
      }
    }
    __syncthreads();
    if (t == 0) cnt_s += wbase[0] + wbase[1] + wbase[2] + wbase[3];
    __syncthreads();
  }
  const int cnt = min(cnt_s, MAXS_);
  if (dc == 0 && b == 0 && t == 0) cntg[w] = cnt;
  // stage proto chunk transposed: protT[d_local][c]
  const float* prb = protos + (size_t)b * NC_ * D_ + dc * 64;
  for (int i = t; i < NC_ * 16; i += 256) {
    int c = i >> 4, d4 = (i & 15) * 4;
    float4 pv = *(const float4*)(prb + (size_t)c * D_ + d4);
    protT[d4 + 0][c] = pv.x; protT[d4 + 1][c] = pv.y;
    protT[d4 + 2][c] = pv.z; protT[d4 + 3][c] = pv.w;
  }
  __syncthreads();   // lpix + protT ready
  // fixed pair assignment: pr = t + 256k  (pr = lp*48 + c)
  const int npair = cnt * NC_;
  int pxk[12], ck[12];
  #pragma unroll
  for (int k = 0; k < 12; ++k) {
    int pr = t + k * 256;
    if (pr < npair) { pxk[k] = lpix[pr / NC_]; ck[k] = pr % NC_; }
    else { pxk[k] = 0; ck[k] = 0; }
  }
  float pacc[12];
  #pragma unroll
  for (int k = 0; k < 12; ++k) pacc[k] = 0.f;
  const float* fw = feats + ((size_t)b * D_ + dc * 64) * HW_ + w0;
  for (int dg = 0; dg < 8; ++dg) {
    #pragma unroll
    for (int k8 = 0; k8 < 8; ++k8) {
      float2 v = *(const float2*)(fw + (size_t)(dg * 8 + k8) * HW_ + t * 2);
      *(float2*)(&rowb[k8][t * 2]) = v;
    }
    __syncthreads();
    const int d = dg * 8;
    #pragma unroll
    for (int k = 0; k < 12; ++k) {
      if (t + k * 256 < npair) {
        const int px = pxk[k], c = ck[k];
        // same 4-term group expression shape as the verified p2 chain
        float t0 = protT[d + 0][c] * rowb[0][px] + protT[d + 1][c] * rowb[1][px]
                 + protT[d + 2][c] * rowb[2][px] + protT[d + 3][c] * rowb[3][px];
        float t1 = protT[d + 4][c] * rowb[4][px] + protT[d + 5][c] * rowb[5][px]
                 + protT[d + 6][c] * rowb[6][px] + protT[d + 7][c] * rowb[7][px];
        float a = pacc[k]; a += t0; a += t1; pacc[k] = a;
      }
    }
    __syncthreads();
  }
  float* pw = pdot + ((size_t)blockIdx.x * B_ + b) * (MAXS_ * NC_);
  #pragma unroll
  for (int k = 0; k < 12; ++k) {
    int pr = t + k * 256;
    if (pr < npair) pw[pr] = pacc[k];
  }
}

// ---------------- P2R: reduce 4 chunks (fixed order) + argmin + map write ----------------
__global__ __launch_bounds__(256) void p2r_kernel(
    const float* __restrict__ pdot, const float* __restrict__ nrmb,
    const int* __restrict__ cntg, const int* __restrict__ gpixg,
    signed char* __restrict__ map) {
  __shared__ float d2b[MAXS_ * NC_];   // 12 KB
  const int w = blockIdx.x, b = blockIdx.y, t = threadIdx.x;
  const int cnt = cntg[w];
  const int npair = cnt * NC_;
  const size_t stride = (size_t)MAXS_ * NC_;
  const float* p0 = pdot + ((size_t)(w * 4 + 0) * B_ + b) * stride;
  const float* p1 = pdot + ((size_t)(w * 4 + 1) * B_ + b) * stride;
  const float* p2 = pdot + ((size_t)(w * 4 + 2) * B_ + b) * stride;
  const float* p3 = pdot + ((size_t)(w * 4 + 3) * B_ + b) * stride;
  const float* nr = nrmb + b * NC_;
  for (int pr = t; pr < npair; pr += 256) {
    float dot = p0[pr];
    dot += p1[pr]; dot += p2[pr]; dot += p3[pr];   // fixed chunk order
    d2b[pr] = nr[pr % NC_] - 2.f * dot;
  }
  __syncthreads();
  if (t < cnt) {
    const float* row = d2b + t * NC_;
    float best = row[0]; int bi = 0;
    for (int c = 1; c < NC_; ++c) {
      float v = row[c];
      if (v < best) { best = v; bi = c; }   // strict '<' keeps first index (np.argmin)
    }
    map[(size_t)b * HW_ + gpixg[w * MAXS_ + t]] = (signed char)bi;
  }
}

// ---------------- M: fused replace + sim GEMM + softmax + outputs (R9/R11-verified, unchanged) ----------------
__global__ __launch_bounds__(128, 2) void m_kernel(
    const float* __restrict__ feats, const float* __restrict__ protos,
    const unsigned short* __restrict__ m_pk, const float* __restrict__ beta,
    const signed char* __restrict__ map,
    float* __restrict__ out_assp, float* __restrict__ out_wmax,
    float* __restrict__ out_sim, float* __restrict__ out_wmean) {
  __shared__ __align__(16) unsigned short Fb[PT_ * 256];   // 16 KB
  __shared__ float wm[PT_];
  __shared__ signed char map_s[PT_];

  const int tid  = threadIdx.x;   // 0..127
  const int lane = tid & 63;
  const int wid  = tid >> 6;      // 0..1
  const int g    = lane >> 4;     // 0..3
  const int lr   = lane & 15;
  const int b    = blockIdx.y;
  const int p0   = blockIdx.x * PT_;

  if (tid < PT_) map_s[tid] = map[(size_t)b * HW_ + p0 + tid];
  __syncthreads();

  unsigned char* fbB = (unsigned char*)Fb;
  const int x  = tid & 7;     // pixel quad: pixels x*4..x*4+3
  const int dr = tid >> 3;    // 0..15

  float V[64];   // V[it*16 + k*4 + j] = F[it*64+dr*4+k][x*4+j]
  {
    const float* fb = feats + (size_t)b * D_ * HW_ + p0 + x * 4;
    const float* prb = protos + (size_t)b * NC_ * D_;
    int cj[4];
    #pragma unroll
    for (int j = 0; j < 4; ++j) cj[j] = map_s[x * 4 + j];
    #pragma unroll
    for (int it = 0; it < 4; ++it) {
      const int d0 = it * 64 + dr * 4;
      #pragma unroll
      for (int k = 0; k < 4; ++k) {
        float4 tv = *(const float4*)(fb + (size_t)(d0 + k) * HW_);
        V[it*16 + k*4 + 0] = tv.x; V[it*16 + k*4 + 1] = tv.y;
        V[it*16 + k*4 + 2] = tv.z; V[it*16 + k*4 + 3] = tv.w;
      }
      #pragma unroll
      for (int j = 0; j < 4; ++j) {
        if (cj[j] >= 0) {
          float4 pv = *(const float4*)(prb + (size_t)cj[j] * D_ + d0);
          V[it*16 + 0*4 + j] = pv.x; V[it*16 + 1*4 + j] = pv.y;
          V[it*16 + 2*4 + j] = pv.z; V[it*16 + 3*4 + j] = pv.w;
        }
      }
      #pragma unroll
      for (int j = 0; j < 4; ++j) {
        const int pw = x * 4 + j;
        const unsigned X = (unsigned)(((pw & 7) << 4) ^ ((pw >> 3) << 3));
        *(ull*)(fbB + pw * 512 + ((unsigned)(d0 * 2) ^ X)) =
            pack4bf(V[it*16 + 0*4 + j], V[it*16 + 1*4 + j],
                    V[it*16 + 2*4 + j], V[it*16 + 3*4 + j]);
      }
    }
  }
  __syncthreads();

  const int p = wid * 16 + lr;
  const unsigned Xp = (unsigned)(((p & 7) << 4) ^ ((p >> 3) << 3));
  f32x4 sacc[3] = {};
  {
    const unsigned short* apk = m_pk + (size_t)b * 24 * 64 * 8 + lane * 8;
    #pragma unroll
    for (int ks = 0; ks < 8; ++ks) {
      const unsigned base = (unsigned)(ks * 64 + g * 16);
      ull lo = *(const ull*)(fbB + p * 512 + (base ^ Xp));
      ull hi = *(const ull*)(fbB + p * 512 + ((base + 8) ^ Xp));
      union { ull u[2]; bf16x8 v8; } bu;
      bu.u[0] = lo; bu.u[1] = hi;
      #pragma unroll
      for (int ct = 0; ct < 3; ++ct) {
        bf16x8 af = *(const bf16x8*)(apk + (size_t)(ks * 3 + ct) * 64 * 8);
        sacc[ct] = __builtin_amdgcn_mfma_f32_16x16x32_bf16(af, bu.v8, sacc[ct], 0, 0, 0);
      }
    }
  }

  #pragma unroll
  for (int ct = 0; ct < 3; ++ct) {
    float4 bt = *(const float4*)(beta + b * NC_ + ct * 16 + g * 4);
    sacc[ct][0] += bt.x; sacc[ct][1] += bt.y;
    sacc[ct][2] += bt.z; sacc[ct][3] += bt.w;
  }
  float m = -3.4e38f;
  #pragma unroll
  for (int ct = 0; ct < 3; ++ct)
    #pragma unroll
    for (int r = 0; r < 4; ++r) m = fmaxf(m, sacc[ct][r]);
  m = fmaxf(m, __shfl_xor(m, 16));
  m = fmaxf(m, __shfl_xor(m, 32));
  const float sc = 1.0f / 6.0f;   // K/C = 8/48
  float s = 0.f;
  #pragma unroll
  for (int ct = 0; ct < 3; ++ct)
    #pragma unroll
    for (int r = 0; r < 4; ++r) s += __expf((sacc[ct][r] - m) * sc);
  s += __shfl_xor(s, 16);
  s += __shfl_xor(s, 32);
  const float wmax = 1.f / s;

  const size_t pixg = (size_t)p0 + p;
  #pragma unroll
  for (int ct = 0; ct < 3; ++ct)
    #pragma unroll
    for (int r = 0; r < 4; ++r)
      out_sim[((size_t)b * NC_ + ct * 16 + g * 4 + r) * HW_ + pixg] = sacc[ct][r];
  if (g == 0) {
    wm[p] = wmax;
    out_wmax[(size_t)b * HW_ + pixg] = wmax;
    out_wmean[(size_t)b * HW_ + pixg] = 1.f / 48.f;
  }
  __syncthreads();

  {
    float4 w4 = *(const float4*)(wm + x * 4);
    float* oa = out_assp + (size_t)b * D_ * HW_ + p0 + x * 4;
    #pragma unroll
    for (int it = 0; it < 4; ++it) {
      const int d0 = it * 64 + dr * 4;
      #pragma unroll
      for (int k = 0; k < 4; ++k) {
        float4 o;
        o.x = V[it*16 + k*4 + 0] * w4.x;
        o.y = V[it*16 + k*4 + 1] * w4.y;
        o.z = V[it*16 + k*4 + 2] * w4.z;
        o.w = V[it*16 + k*4 + 3] * w4.w;
        *(float4*)(oa + (size_t)(d0 + k) * HW_) = o;
      }
    }
  }
}

extern "C" void kernel_launch(void* const* d_in, const int* in_sizes, int n_in,
                              void* d_out, int out_size, void* d_ws, size_t ws_size,
                              hipStream_t stream) {
  const float* feats  = (const float*)d_in[0];
  const float* protos = (const float*)d_in[1];
  const float* Wk     = (const float*)d_in[2];
  const float* bk     = (const float*)d_in[3];
  const float* Wq     = (const float*)d_in[4];
  const float* bq     = (const float*)d_in[5];
  const int*   xc     = (const int*)d_in[6];
  const int*   yc     = (const int*)d_in[7];
  const int    P      = in_sizes[6];   // 819

  float* out       = (float*)d_out;
  float* out_assp  = out;                                  // B*D*HW
  float* out_po    = out_assp + (size_t)B_ * D_ * HW_;     // 48*B*128
  float* out_wmax  = out_po + (size_t)NC_ * B_ * KO_;      // B*HW
  float* out_sim   = out_wmax + (size_t)B_ * HW_;          // B*48*HW
  float* out_wmean = out_sim + (size_t)B_ * NC_ * HW_;     // B*HW

  unsigned char* ws = (unsigned char*)d_ws;
  unsigned short* m_pk = (unsigned short*)ws;                    // 196608 B
  float* beta          = (float*)(ws + 196608);                  // 1536 B
  float* nrmb          = (float*)(ws + 198144);                  // 1536 B
  int* pixlist         = (int*)(ws + 199680);                    // 3584 B
  signed char* map     = (signed char*)(ws + 203264);            // 131072 B -> 334336

  // scratch block: [cntg 128B][gpixg 8192B][pad->8704][pdot 12.58MB]
  const size_t scr_off   = 334336;
  const size_t pdot_off  = 8704;
  const size_t pdot_byte = (size_t)NW_ * NDC_ * B_ * MAXS_ * NC_ * 4;  // 12,582,912
  unsigned char* scr = (ws_size >= scr_off + pdot_off + pdot_byte)
                     ? (ws + scr_off) : (unsigned char*)out_sim;  // out_sim written later by m
  int*   cntg  = (int*)scr;
  int*   gpixg = (int*)(scr + 128);
  float* pdot  = (float*)(scr + pdot_off);

  p1_kernel<<<dim3(NC_, B_), 256, 0, stream>>>(protos, Wq, bq, Wk, bk, xc, yc,
                                               m_pk, beta, nrmb, out_po,
                                               (int*)map, pixlist, P);
  pd_kernel<<<dim3(NW_ * NDC_, B_), 256, 0, stream>>>(feats, protos, pixlist, P,
                                                      pdot, cntg, gpixg);
  p2r_kernel<<<dim3(NW_, B_), 256, 0, stream>>>(pdot, nrmb, cntg, gpixg, map);
  m_kernel<<<dim3(HW_ / PT_, B_), 128, 0, stream>>>(feats, protos, m_pk, beta, map,
                                                    out_assp, out_wmax, out_sim, out_wmean);
}